// Round 2
// baseline (77.569 us; speedup 1.0000x reference)
//
#include <hip/hip_runtime.h>

#define NBINS 10
#define TPB 256
#define CSTRIDE 257                 // 256 thread-columns + 1 pad
#define ROWS (3 * NBINS)            // [cnt×10 | su×10 | se×10]
#define LDSN (ROWS * CSTRIDE)       // 7710 f32 = 30840 B -> 5 blocks/CU

__global__ void uce_zero(float* __restrict__ acc) {
    int i = threadIdx.x;
    if (i < ROWS) acc[i] = 0.0f;
}

__global__ __launch_bounds__(TPB) void uce_hist(const float* __restrict__ up,
                                                const float* __restrict__ ep,
                                                float* __restrict__ acc, int n4) {
    __shared__ float h[LDSN];
    int tid = threadIdx.x;
    for (int i = tid; i < LDSN; i += TPB) h[i] = 0.0f;
    __syncthreads();

    const float4* __restrict__ u4 = (const float4*)up;
    const float4* __restrict__ e4 = (const float4*)ep;
    int stride = gridDim.x * TPB;
    for (int i = blockIdx.x * TPB + tid; i < n4; i += stride) {
        float4 uu = u4[i];
        float4 ee = e4[i];
        float us[4] = {uu.x, uu.y, uu.z, uu.w};
        float es[4] = {ee.x, ee.y, ee.z, ee.w};
#pragma unroll
        for (int k = 0; k < 4; ++k) {
            float u = us[k], e = es[k];
            // FROZEN binning (bit-exact vs reference, absmax 0.0 in R0):
            // bin i iff fl(i*0.1f) < u <= fl((i+1)*0.1f)
            int g = (int)(u * 10.0f);
            g = g > 9 ? 9 : g;
            float gf = (float)g;
            float lo = gf * 0.1f;
            float hi = (gf + 1.0f) * 0.1f;     // == (float)(g+1)*0.1f exactly
            g += (u > hi) ? 1 : 0;             // conditions mutually exclusive
            g -= (u <= lo) ? 1 : 0;            // u<=0 -> -1; u>1.0 -> 10
            bool valid = (g >= 0) && (g <= 9);
            float sel = valid ? 1.0f : 0.0f;
            int ga = valid ? g : 0;
            int idx = ga * CSTRIDE + tid;      // private column per thread
            float c = h[idx];
            float s = h[idx + NBINS * CSTRIDE];
            float t = h[idx + 2 * NBINS * CSTRIDE];
            h[idx]                      = c + sel;
            h[idx + NBINS * CSTRIDE]    = fmaf(sel, u, s);
            h[idx + 2 * NBINS * CSTRIDE] = fmaf(sel, e, t);
        }
    }
    __syncthreads();

    // Block reduce: 8 threads per row, 32 columns each (cols 0..255 only).
    int r = tid >> 3, sub = tid & 7;
    if (r < ROWS) {
        float s = 0.0f;
        int base = r * CSTRIDE + sub * 32;
#pragma unroll
        for (int c = 0; c < 32; ++c) s += h[base + c];
        s += __shfl_down(s, 4, 8);
        s += __shfl_down(s, 2, 8);
        s += __shfl_down(s, 1, 8);
        if (sub == 0) atomicAdd(&acc[r], s);
    }
}

__global__ void uce_final(const float* __restrict__ acc, float* __restrict__ out,
                          float inv_n) {
    if (threadIdx.x == 0 && blockIdx.x == 0) {
        float uce = 0.0f;
#pragma unroll
        for (int b = 0; b < NBINS; ++b) {
            float c = acc[b];
            if (c > 0.0f) {
                float au = acc[NBINS + b] / c;
                float ae = acc[2 * NBINS + b] / c;
                uce += fabsf(au - ae) * (c * inv_n);
            }
        }
        out[0] = uce;
    }
}

extern "C" void kernel_launch(void* const* d_in, const int* in_sizes, int n_in,
                              void* d_out, int out_size, void* d_ws, size_t ws_size,
                              hipStream_t stream) {
    const float* u = (const float*)d_in[0];
    const float* e = (const float*)d_in[1];
    float* acc = (float*)d_ws;
    float* out = (float*)d_out;
    int n = in_sizes[0];
    int n4 = n >> 2;

    uce_zero<<<1, 64, 0, stream>>>(acc);
    uce_hist<<<1280, TPB, 0, stream>>>(u, e, acc, n4);  // 5 blocks/CU x 256 CU
    uce_final<<<1, 64, 0, stream>>>(acc, out, 1.0f / (float)n);
}